// Round 1
// baseline (86.990 us; speedup 1.0000x reference)
//
#include <hip/hip_runtime.h>

// opool: x [B, D*C, h, w], D=12. Per (b,c) group of 12 contiguous h*w maps,
// flat argmax over (D,h,w) -> winning orientation d; output that h*w map.
// B=8, C=64, h=w=128. groups = 512, each group = 196608 contiguous floats.

constexpr int D_ORI  = 12;
constexpr int HW     = 128 * 128;          // 16384
constexpr int GROUP  = D_ORI * HW;         // 196608
constexpr int BLOCK  = 1024;
constexpr int NWAVES = BLOCK / 64;         // 16

__global__ __launch_bounds__(BLOCK) void opool_kernel(const float* __restrict__ x,
                                                      float* __restrict__ out) {
    const int g = blockIdx.x;                       // group id in [0, B*C)
    const float* __restrict__ gx = x + (size_t)g * GROUP;
    const int tid = threadIdx.x;

    // ---- Phase 1: argmax over GROUP floats (first-occurrence tie-break) ----
    float best = -__builtin_huge_valf();
    int   bidx = 0x7fffffff;

    const float4* __restrict__ gx4 = reinterpret_cast<const float4*>(gx);
    constexpr int NV = GROUP / 4;                   // 49152 float4
    for (int k = tid; k < NV; k += BLOCK) {
        float4 v = gx4[k];
        const int base = k << 2;
        // strict > keeps earliest index within a thread's ascending scan
        if (v.x > best) { best = v.x; bidx = base;     }
        if (v.y > best) { best = v.y; bidx = base + 1; }
        if (v.z > best) { best = v.z; bidx = base + 2; }
        if (v.w > best) { best = v.w; bidx = base + 3; }
    }

    // wave-64 butterfly reduce of (val, idx), min-idx tie-break
    #pragma unroll
    for (int off = 32; off >= 1; off >>= 1) {
        float ov = __shfl_xor(best, off, 64);
        int   oi = __shfl_xor(bidx, off, 64);
        if (ov > best || (ov == best && oi < bidx)) { best = ov; bidx = oi; }
    }

    __shared__ float s_val[NWAVES];
    __shared__ int   s_idx[NWAVES];
    __shared__ int   s_d;
    const int wave = tid >> 6;
    if ((tid & 63) == 0) { s_val[wave] = best; s_idx[wave] = bidx; }
    __syncthreads();
    if (tid == 0) {
        float bv = s_val[0]; int bi = s_idx[0];
        #pragma unroll
        for (int i = 1; i < NWAVES; ++i) {
            if (s_val[i] > bv || (s_val[i] == bv && s_idx[i] < bi)) {
                bv = s_val[i]; bi = s_idx[i];
            }
        }
        s_d = bi / HW;                               // winning orientation
    }
    __syncthreads();
    const int d = s_d;

    // ---- Phase 2: copy winning h*w map to output ----
    const float4* __restrict__ src = reinterpret_cast<const float4*>(gx + (size_t)d * HW);
    float4* __restrict__ dst = reinterpret_cast<float4*>(out + (size_t)g * HW);
    constexpr int NC = HW / 4;                       // 4096 float4
    for (int k = tid; k < NC; k += BLOCK) dst[k] = src[k];
}

extern "C" void kernel_launch(void* const* d_in, const int* in_sizes, int n_in,
                              void* d_out, int out_size, void* d_ws, size_t ws_size,
                              hipStream_t stream) {
    const float* x  = (const float*)d_in[0];
    float* out      = (float*)d_out;
    const int ngroups = in_sizes[0] / GROUP;         // B*C = 512
    opool_kernel<<<ngroups, BLOCK, 0, stream>>>(x, out);
}

// Round 2
// 86.613 us; speedup vs baseline: 1.0044x; 1.0044x over previous
//
#include <hip/hip_runtime.h>

// opool: x [B, D*C, h, w], D=12. Per (b,c) group of 12 contiguous h*w maps,
// flat argmax over (D,h,w) -> winning orientation d; output that h*w map.
// B=8, C=64, h=w=128 -> 512 groups, 196608 contiguous floats each.

constexpr int D_ORI = 12;
constexpr int HW    = 128 * 128;            // 16384 floats
constexpr int GROUP = D_ORI * HW;           // 196608 floats
constexpr int PARTS = 8;                    // sub-blocks per group
constexpr int BLOCK = 256;                  // 4 waves
constexpr int PART_F4 = GROUP / PARTS / 4;  // 6144 float4 per part
constexpr int SLICE_F4 = HW / PARTS / 4;    // 512 float4 per copy slice

// order-preserving float -> u32 (monotone; no NaN in inputs)
__device__ __forceinline__ unsigned int fkey(float f) {
    unsigned int u = __float_as_uint(f);
    return (u & 0x80000000u) ? ~u : (u | 0x80000000u);
}

// Kernel 1: per-(group,part) partial argmax -> packed u64 in ws.
// packed = (fkey(val) << 32) | ~idx  => max() == (max val, min idx).
__global__ __launch_bounds__(BLOCK) void opool_scan(const float* __restrict__ x,
                                                    unsigned long long* __restrict__ ws) {
    const int g    = blockIdx.x / PARTS;
    const int part = blockIdx.x % PARTS;
    const float4* __restrict__ p4 =
        reinterpret_cast<const float4*>(x + (size_t)g * GROUP) + (size_t)part * PART_F4;
    const int tid = threadIdx.x;
    const int idx_base0 = part * PART_F4 * 4;   // flat idx offset within group

    // dual accumulators to halve the dependent cmp-chain depth
    float b0 = -__builtin_huge_valf(), b1 = -__builtin_huge_valf();
    int   i0 = 0x7fffffff,             i1 = 0x7fffffff;

    #pragma unroll 4
    for (int k = tid; k < PART_F4; k += 2 * BLOCK) {
        float4 v = p4[k];
        const int base = idx_base0 + (k << 2);
        if (v.x > b0) { b0 = v.x; i0 = base;     }
        if (v.y > b0) { b0 = v.y; i0 = base + 1; }
        if (v.z > b0) { b0 = v.z; i0 = base + 2; }
        if (v.w > b0) { b0 = v.w; i0 = base + 3; }
        const int k2 = k + BLOCK;
        if (k2 < PART_F4) {
            float4 w = p4[k2];
            const int base2 = idx_base0 + (k2 << 2);
            if (w.x > b1) { b1 = w.x; i1 = base2;     }
            if (w.y > b1) { b1 = w.y; i1 = base2 + 1; }
            if (w.z > b1) { b1 = w.z; i1 = base2 + 2; }
            if (w.w > b1) { b1 = w.w; i1 = base2 + 3; }
        }
    }
    // merge accumulators (min idx on tie)
    if (b1 > b0 || (b1 == b0 && i1 < i0)) { b0 = b1; i0 = i1; }

    unsigned long long packed =
        ((unsigned long long)fkey(b0) << 32) | (unsigned int)(~i0);

    // wave-64 butterfly max
    #pragma unroll
    for (int off = 32; off >= 1; off >>= 1) {
        unsigned long long o = __shfl_xor(packed, off, 64);
        if (o > packed) packed = o;
    }
    __shared__ unsigned long long s[BLOCK / 64];
    const int wave = tid >> 6;
    if ((tid & 63) == 0) s[wave] = packed;
    __syncthreads();
    if (tid == 0) {
        #pragma unroll
        for (int i = 1; i < BLOCK / 64; ++i)
            if (s[i] > packed) packed = s[i];
        ws[blockIdx.x] = packed;
    }
}

// Kernel 2: reduce 8 partials per group (L2-hot), copy 1/8 of winning map.
__global__ __launch_bounds__(BLOCK) void opool_copy(const float* __restrict__ x,
                                                    const unsigned long long* __restrict__ ws,
                                                    float* __restrict__ out) {
    const int g = blockIdx.x / PARTS;
    const int j = blockIdx.x % PARTS;

    const unsigned long long* wg = ws + (size_t)g * PARTS;
    unsigned long long best = wg[0];
    #pragma unroll
    for (int i = 1; i < PARTS; ++i) {
        unsigned long long v = wg[i];
        if (v > best) best = v;
    }
    const int idx = (int)(~(unsigned int)best);
    const int d   = idx / HW;

    const float4* __restrict__ src =
        reinterpret_cast<const float4*>(x + (size_t)g * GROUP + (size_t)d * HW) + (size_t)j * SLICE_F4;
    float4* __restrict__ dst =
        reinterpret_cast<float4*>(out + (size_t)g * HW) + (size_t)j * SLICE_F4;

    const int tid = threadIdx.x;
    #pragma unroll
    for (int k = tid; k < SLICE_F4; k += BLOCK) dst[k] = src[k];
}

extern "C" void kernel_launch(void* const* d_in, const int* in_sizes, int n_in,
                              void* d_out, int out_size, void* d_ws, size_t ws_size,
                              hipStream_t stream) {
    const float* x = (const float*)d_in[0];
    float* out     = (float*)d_out;
    unsigned long long* ws = (unsigned long long*)d_ws;
    const int ngroups = in_sizes[0] / GROUP;        // 512
    const int nblocks = ngroups * PARTS;            // 4096

    opool_scan<<<nblocks, BLOCK, 0, stream>>>(x, ws);
    opool_copy<<<nblocks, BLOCK, 0, stream>>>(x, ws, out);
}